// Round 1
// baseline (221.892 us; speedup 1.0000x reference)
//
#include <hip/hip_runtime.h>
#include <cstdint>
#include <cstddef>

#define B_   128
#define NF_  64
#define L_   4096
#define K_   64
#define NG_  400

// ---------------------------------------------------------------------------
// Kernel A: filtered[b,f] = (1/L) * sum_{g,l} X[b,g,l] * amps[f,g]
//                            * exp(-(x_l - mus[f,g])^2 / (2*16^2))
// x_l = l * (4096/4095)  (jnp.linspace(0, 4096, 4096), endpoint=True)
// Gaussian truncated to a 192-sample window around mu (tail < 1e-7).
// One block per (b,g): stage the X row in LDS (padded), 4-lane groups each
// own one of 64 filters, atomicAdd partial into filtered (zeroed beforehand).
// ---------------------------------------------------------------------------
__global__ __launch_bounds__(256) void filt_kernel(
    const float* __restrict__ X, const float* __restrict__ mus,
    const float* __restrict__ amps, float* __restrict__ filtered)
{
    const int g = blockIdx.x;
    const int b = blockIdx.y;

    __shared__ __align__(16) float Xs[128 + L_ + 128];  // zero-padded row
    __shared__ float mu_s[NF_];
    __shared__ float sc_s[NF_];

    const int t = threadIdx.x;

    // zero pads + gather per-(f,g) mu/amp (strided by NG, tiny & L2-resident)
    if (t < 128) { Xs[t] = 0.0f; Xs[128 + L_ + t] = 0.0f; }
    else if (t < 192) { int f = t - 128; mu_s[f] = mus[f * NG_ + g]; }
    else              { int f = t - 192; sc_s[f] = amps[f * NG_ + g] * (1.0f / 4096.0f); }

    // coalesced float4 staging of the 4096-float row
    const float4* __restrict__ row = (const float4*)(X + ((size_t)b * NG_ + g) * L_);
    float4* Xs4 = (float4*)(Xs + 128);
#pragma unroll
    for (int r = 0; r < 4; ++r) Xs4[t + 256 * r] = row[t + 256 * r];
    __syncthreads();

    const int lane = t & 63;
    const int w    = t >> 6;          // wave id: 4 waves x 16 filters
    const int i    = lane & 3;        // sub-lane within 4-lane filter group
    const int f    = w * 16 + (lane >> 2);

    const float mu = mu_s[f];
    const int   l0 = (((int)mu) - 96) & ~3;   // 16B-aligned window start

    constexpr float STEP = 4096.0f / 4095.0f;
    constexpr float NEGC = -1.4426950408889634f / 512.0f;  // -log2(e)/(2*sigma^2)

    const float4* src = (const float4*)(Xs + 128 + l0 + i * 4);
    const float lb0 = (float)(l0 + i * 4);
    float acc = 0.0f;
#pragma unroll 4
    for (int itr = 0; itr < 12; ++itr) {       // 12 * 16 = 192 samples/filter
        float4 v = src[itr * 4];
        float base = lb0 + 16.0f * itr;
        float d0 = fmaf(base + 0.0f, STEP, -mu);
        float d1 = fmaf(base + 1.0f, STEP, -mu);
        float d2 = fmaf(base + 2.0f, STEP, -mu);
        float d3 = fmaf(base + 3.0f, STEP, -mu);
        acc = fmaf(v.x, exp2f(d0 * d0 * NEGC), acc);
        acc = fmaf(v.y, exp2f(d1 * d1 * NEGC), acc);
        acc = fmaf(v.z, exp2f(d2 * d2 * NEGC), acc);
        acc = fmaf(v.w, exp2f(d3 * d3 * NEGC), acc);
    }
    // reduce the 4-lane group
    acc += __shfl_xor(acc, 1);
    acc += __shfl_xor(acc, 2);
    if (i == 0) atomicAdd(&filtered[b * NF_ + f], acc * sc_s[f]);
}

// ---------------------------------------------------------------------------
// Kernel B: the MLP head. One block per batch row; tiny.
//   mu      = elu(filtered @ Wmu^T  + bmu)
//   log_sig = elu(filtered @ Wsig^T + bsig)
//   latent  = mu + eps * exp(log_sig)
//   h       = gelu(latent @ W01^T + b01)          (exact gelu)
//   coms    = gelu(h @ W1^T + b1)
//   pred    = gelu(h @ W2^T + b2)
// out layout: coms[128*400] | pred[128*400] | mu[128*64] | log_sig[128*64]
// ---------------------------------------------------------------------------
__device__ __forceinline__ float gelu_exact(float x) {
    return 0.5f * x * (1.0f + erff(x * 0.70710678118654752f));
}

__global__ __launch_bounds__(256) void head_kernel(
    const float* __restrict__ filtered, const float* __restrict__ eps,
    const float* __restrict__ Wmu,  const float* __restrict__ bmu,
    const float* __restrict__ Wsig, const float* __restrict__ bsig,
    const float* __restrict__ W01,  const float* __restrict__ b01,
    const float* __restrict__ W1,   const float* __restrict__ b1,
    const float* __restrict__ W2,   const float* __restrict__ b2,
    float* __restrict__ out)
{
    const int b = blockIdx.x;
    const int t = threadIdx.x;
    __shared__ float fil[NF_], lat[K_], hh[K_];

    if (t < NF_) fil[t] = filtered[b * NF_ + t];
    __syncthreads();

    if (t < K_) {
        float am = bmu[t], as = bsig[t];
#pragma unroll 8
        for (int fj = 0; fj < NF_; ++fj) {
            float x = fil[fj];
            am = fmaf(x, Wmu [t * NF_ + fj], am);
            as = fmaf(x, Wsig[t * NF_ + fj], as);
        }
        float muv = am > 0.0f ? am : expm1f(am);
        float lsv = as > 0.0f ? as : expm1f(as);
        out[2 * B_ * NG_            + b * K_ + t] = muv;   // mu section
        out[2 * B_ * NG_ + B_ * K_  + b * K_ + t] = lsv;   // log_sig section
        lat[t] = fmaf(eps[b * K_ + t], expf(lsv), muv);
    }
    __syncthreads();

    if (t < K_) {
        float a = b01[t];
#pragma unroll 8
        for (int j = 0; j < K_; ++j) a = fmaf(lat[j], W01[t * K_ + j], a);
        hh[t] = gelu_exact(a);
    }
    __syncthreads();

    for (int n = t; n < NG_; n += 256) {
        float a1 = b1[n], a2 = b2[n];
#pragma unroll 8
        for (int k = 0; k < K_; ++k) {
            float hk = hh[k];
            a1 = fmaf(hk, W1[n * K_ + k], a1);
            a2 = fmaf(hk, W2[n * K_ + k], a2);
        }
        out[            b * NG_ + n] = gelu_exact(a1);   // coms
        out[B_ * NG_ +  b * NG_ + n] = gelu_exact(a2);   // pred_num_spikes
    }
}

extern "C" void kernel_launch(void* const* d_in, const int* in_sizes, int n_in,
                              void* d_out, int out_size, void* d_ws, size_t ws_size,
                              hipStream_t stream) {
    const float* X    = (const float*)d_in[0];
    const float* eps  = (const float*)d_in[1];
    const float* mus  = (const float*)d_in[2];
    const float* amps = (const float*)d_in[3];
    const float* Wmu  = (const float*)d_in[4];
    const float* bmu  = (const float*)d_in[5];
    const float* Wsig = (const float*)d_in[6];
    const float* bsig = (const float*)d_in[7];
    const float* W01  = (const float*)d_in[8];
    const float* b01  = (const float*)d_in[9];
    const float* W1   = (const float*)d_in[10];
    const float* b1   = (const float*)d_in[11];
    const float* W2   = (const float*)d_in[12];
    const float* b2   = (const float*)d_in[13];

    float* out      = (float*)d_out;
    float* filtered = (float*)d_ws;   // B_*NF_ f32 accumulator

    // zero the atomic accumulator every call (harness does not re-poison)
    hipMemsetAsync(filtered, 0, B_ * NF_ * sizeof(float), stream);

    filt_kernel<<<dim3(NG_, B_), 256, 0, stream>>>(X, mus, amps, filtered);
    head_kernel<<<B_, 256, 0, stream>>>(filtered, eps, Wmu, bmu, Wsig, bsig,
                                        W01, b01, W1, b1, W2, b2, out);
}